// Round 1
// baseline (1346.265 us; speedup 1.0000x reference)
//
#include <hip/hip_runtime.h>
#include <hip/hip_bf16.h>

typedef float f32x4 __attribute__((ext_vector_type(4)));
typedef short s16x8 __attribute__((ext_vector_type(8)));
typedef short s16x4 __attribute__((ext_vector_type(4)));

#define HW 65536
#define MFMA16(a,b,c) __builtin_amdgcn_mfma_f32_16x16x32_bf16((a),(b),(c),0,0,0)

__device__ __forceinline__ short bfr(float f){
  __hip_bfloat16 h = __float2bfloat16(f);
  return __builtin_bit_cast(short, h);
}
__device__ __forceinline__ float b2f(short s){
  unsigned u = ((unsigned)(unsigned short)s) << 16;
  return __builtin_bit_cast(float, u);
}

// ---------------- weight pack: [co][ci][3][3] f32 -> [conv][tap][co][ci] bf16 ----------------
__global__ __launch_bounds__(256) void kpack(const float* __restrict__ a, const float* __restrict__ b,
                                             const float* __restrict__ c, const float* __restrict__ d,
                                             unsigned short* __restrict__ wp){
  int i = blockIdx.x*256 + threadIdx.x;
  if(i >= 4*9*64*64) return;
  int ci = i & 63, co = (i>>6) & 63, te = i >> 12;
  int tap = te % 9, cv = te / 9;
  const float* s = (cv==0)?a:(cv==1)?b:(cv==2)?c:d;
  wp[i] = (unsigned short)bfr(s[(co*64+ci)*9 + tap]);
}

// ---------------- Gram partials: per-block Gxx/Gxy/Gyy (64x64) + sx/sy over 512 px ----------------
// grid 1024 = 8 batches x 128 groups; 4 waves process the SAME 32 px, wave w owns row-group w.
__global__ __launch_bounds__(256) void kgram(const float* __restrict__ x, const float* __restrict__ y,
                                             float* __restrict__ part){
  const int bid = blockIdx.x;
  const int b = bid >> 7, g = bid & 127;
  const int t = threadIdx.x, w = t >> 6, l = t & 63;
  const int c16 = l & 15, kg = l >> 4;
  const float* xb = x + (size_t)b*64*HW;
  const float* yb = y + (size_t)b*64*HW;
  f32x4 gxx[4], gxy[4], gyy[4];
  #pragma unroll
  for(int i=0;i<4;++i){ gxx[i]=(f32x4){0.f,0.f,0.f,0.f}; gxy[i]=gxx[i]; gyy[i]=gxx[i]; }
  float sxp[4]={0.f,0.f,0.f,0.f}, syp[4]={0.f,0.f,0.f,0.f};
  for(int it=0; it<16; ++it){
    const int px = g*512 + it*32 + kg*8;
    s16x8 fx[4], fy[4], ax, ay;
    #pragma unroll
    for(int mi=0; mi<4; ++mi){
      const float* p = xb + (size_t)(mi*16+c16)*HW + px;
      f32x4 u0 = *(const f32x4*)p, u1 = *(const f32x4*)(p+4);
      #pragma unroll
      for(int j=0;j<4;++j){ fx[mi][j] = bfr(u0[j]); fx[mi][4+j] = bfr(u1[j]); }
      sxp[mi] += u0[0]+u0[1]+u0[2]+u0[3]+u1[0]+u1[1]+u1[2]+u1[3];
      const float* q = yb + (size_t)(mi*16+c16)*HW + px;
      f32x4 v0 = *(const f32x4*)q, v1 = *(const f32x4*)(q+4);
      #pragma unroll
      for(int j=0;j<4;++j){ fy[mi][j] = bfr(v0[j]); fy[mi][4+j] = bfr(v1[j]); }
      syp[mi] += v0[0]+v0[1]+v0[2]+v0[3]+v1[0]+v1[1]+v1[2]+v1[3];
    }
    { // wave's own A-fragment (row-group w) — loaded explicitly to avoid runtime reg-array index
      const float* p = xb + (size_t)(w*16+c16)*HW + px;
      f32x4 u0 = *(const f32x4*)p, u1 = *(const f32x4*)(p+4);
      #pragma unroll
      for(int j=0;j<4;++j){ ax[j] = bfr(u0[j]); ax[4+j] = bfr(u1[j]); }
      const float* q = yb + (size_t)(w*16+c16)*HW + px;
      f32x4 v0 = *(const f32x4*)q, v1 = *(const f32x4*)(q+4);
      #pragma unroll
      for(int j=0;j<4;++j){ ay[j] = bfr(v0[j]); ay[4+j] = bfr(v1[j]); }
    }
    #pragma unroll
    for(int ni=0; ni<4; ++ni){
      gxx[ni] = MFMA16(ax, fx[ni], gxx[ni]);
      gxy[ni] = MFMA16(ax, fy[ni], gxy[ni]);
      gyy[ni] = MFMA16(ay, fy[ni], gyy[ni]);
    }
  }
  float* P = part + (size_t)bid*12416;
  #pragma unroll
  for(int ni=0; ni<4; ++ni)
    #pragma unroll
    for(int r=0;r<4;++r){
      int row = w*16 + kg*4 + r, col = ni*16 + c16;
      P[row*64+col]        = gxx[ni][r];
      P[4096 + row*64+col] = gxy[ni][r];
      P[8192 + row*64+col] = gyy[ni][r];
    }
  #pragma unroll
  for(int mi=0; mi<4; ++mi){
    float v = (w==0) ? sxp[mi] : syp[mi];
    v += __shfl_xor(v, 16);
    v += __shfl_xor(v, 32);
    if(kg==0){
      if(w==0) P[12288 + mi*16 + c16] = v;
      else if(w==1) P[12352 + mi*16 + c16] = v;
    }
  }
}

// ---------------- attention algebra: S=Wq G Wk^T + bias terms, softmax, Weff=attn*Wv ----------------
__global__ __launch_bounds__(256) void kattn(const float* __restrict__ qw, const float* __restrict__ qb,
                                             const float* __restrict__ kw2, const float* __restrict__ kb,
                                             const float* __restrict__ vw, const float* __restrict__ vb,
                                             const float* __restrict__ part,
                                             unsigned short* __restrict__ Wb, float* __restrict__ beff){
  const int b = blockIdx.x, t = threadIdx.x;
  __shared__ float Gs[4096];
  __shared__ float T[4096];
  __shared__ float S[4096];
  __shared__ float uq[64], uk[64], nq[64], nk[64], sxs[64], sys[64];
  __shared__ float A[64*16];
  const float* PB = part + (size_t)b*128*12416;

  // (1) Gs = sum Gxy partials; sxs/sys
  for(int idx=t; idx<4096; idx+=256){
    float a=0; for(int p=0;p<128;++p) a += PB[(size_t)p*12416 + 4096 + idx];
    Gs[idx]=a;
  }
  if(t<64){
    float a=0,e=0;
    for(int p=0;p<128;++p){ a += PB[(size_t)p*12416 + 12288 + t]; e += PB[(size_t)p*12416 + 12352 + t]; }
    sxs[t]=a; sys[t]=e;
  }
  __syncthreads();
  // (2) uq/uk ; T1 = Gxy * Wk^T
  if(t<64){
    float a=0,e=0;
    for(int i=0;i<64;++i){ a += qw[t*64+i]*sxs[i]; e += kw2[t*64+i]*sys[i]; }
    uq[t]=a; uk[t]=e;
  }
  for(int idx=t; idx<4096; idx+=256){
    int i = idx>>6, d = idx&63; float a=0;
    for(int j=0;j<64;++j) a += Gs[i*64+j]*kw2[d*64+j];
    T[idx]=a;
  }
  __syncthreads();
  // (3) S = Wq*T1 + biases ; Gs = Gxx
  for(int idx=t; idx<4096; idx+=256){
    int c = idx>>6, d = idx&63; float a=0;
    for(int i=0;i<64;++i) a += qw[c*64+i]*T[i*64+d];
    S[idx] = a + qb[c]*uk[d] + uq[c]*kb[d] + 65536.f*qb[c]*kb[d];
  }
  for(int idx=t; idx<4096; idx+=256){
    float a=0; for(int p=0;p<128;++p) a += PB[(size_t)p*12416 + idx];
    Gs[idx]=a;
  }
  __syncthreads();
  // (4) T2 = Gxx * Wq^T
  for(int idx=t; idx<4096; idx+=256){
    int i = idx>>6, c = idx&63; float a=0;
    for(int j=0;j<64;++j) a += Gs[i*64+j]*qw[c*64+j];
    T[idx]=a;
  }
  __syncthreads();
  // (5) nq ; Gs = Gyy
  if(t<64){
    float a=0; for(int i=0;i<64;++i) a += qw[t*64+i]*T[i*64+t];
    a += 2.f*qb[t]*uq[t] + 65536.f*qb[t]*qb[t];
    nq[t] = fmaxf(sqrtf(fmaxf(a,0.f)), 1e-12f);
  }
  for(int idx=t; idx<4096; idx+=256){
    float a=0; for(int p=0;p<128;++p) a += PB[(size_t)p*12416 + 8192 + idx];
    Gs[idx]=a;
  }
  __syncthreads();
  // (6) T3 = Gyy * Wk^T
  for(int idx=t; idx<4096; idx+=256){
    int i = idx>>6, d = idx&63; float a=0;
    for(int j=0;j<64;++j) a += Gs[i*64+j]*kw2[d*64+j];
    T[idx]=a;
  }
  __syncthreads();
  // (7) nk
  if(t<64){
    float a=0; for(int i=0;i<64;++i) a += kw2[t*64+i]*T[i*64+t];
    a += 2.f*kb[t]*uk[t] + 65536.f*kb[t]*kb[t];
    nk[t] = fmaxf(sqrtf(fmaxf(a,0.f)), 1e-12f);
  }
  __syncthreads();
  // (8) per-row softmax within head
  if(t<64){
    int h = t>>4;
    float L[16], m=-1e30f;
    #pragma unroll
    for(int d=0; d<16; ++d){ L[d] = S[t*64 + h*16 + d] / (nq[t]*nk[h*16+d]); m = fmaxf(m, L[d]); }
    float s=0;
    #pragma unroll
    for(int d=0;d<16;++d){ L[d]=expf(L[d]-m); s+=L[d]; }
    float inv = 1.f/s;
    #pragma unroll
    for(int d=0;d<16;++d) A[t*16+d] = L[d]*inv;
  }
  __syncthreads();
  // (9) Weff (bf16) and beff
  for(int idx=t; idx<4096; idx+=256){
    int c = idx>>6, j = idx&63, h = c>>4;
    float a=0;
    #pragma unroll
    for(int d=0;d<16;++d) a += A[c*16+d]*vw[(h*16+d)*64 + j];
    Wb[(size_t)b*4096 + idx] = (unsigned short)bfr(a);
  }
  if(t<64){
    int h=t>>4; float a=0;
    #pragma unroll
    for(int d=0;d<16;++d) a += A[t*16+d]*vb[h*16+d];
    beff[b*64+t] = a;
  }
}

// ---------------- out0 = Weff[b] * y + beff : 1x1 conv via MFMA, channels-last bf16 out ----------------
__global__ __launch_bounds__(256) void k1x1(const float* __restrict__ y, const unsigned short* __restrict__ Wb,
                                            const float* __restrict__ beff, unsigned short* __restrict__ out0){
  const int b = blockIdx.x >> 10, px0 = (blockIdx.x & 1023) << 6;
  const int t = threadIdx.x;
  __shared__ unsigned short ylds[4096];
  {
    const int ci = t >> 2, q = t & 3;
    const float* p = y + (size_t)b*64*HW + (size_t)ci*HW + px0 + q*16;
    f32x4 v0 = *(const f32x4*)p, v1 = *(const f32x4*)(p+4);
    f32x4 v2 = *(const f32x4*)(p+8), v3 = *(const f32x4*)(p+12);
    float vv[16] = {v0[0],v0[1],v0[2],v0[3], v1[0],v1[1],v1[2],v1[3],
                    v2[0],v2[1],v2[2],v2[3], v3[0],v3[1],v3[2],v3[3]};
    #pragma unroll
    for(int i=0;i<16;++i){
      int pl = q*16 + i;
      int byte = pl*128 + ((ci*2) ^ ((pl&7)<<4));
      *(short*)((char*)ylds + byte) = bfr(vv[i]);
    }
  }
  __syncthreads();
  const int w = t >> 6, l = t & 63, c16 = l & 15, kg = l >> 4;
  f32x4 acc[4];
  #pragma unroll
  for(int i=0;i<4;++i) acc[i]=(f32x4){0.f,0.f,0.f,0.f};
  #pragma unroll
  for(int kh=0; kh<2; ++kh){
    const int p = w*16 + c16;
    const int byte = p*128 + (((kh*32 + kg*8)*2) ^ ((p&7)<<4));
    s16x8 bf = *(const s16x8*)((char*)ylds + byte);
    #pragma unroll
    for(int mi=0; mi<4; ++mi){
      s16x8 af = *(const s16x8*)(Wb + (size_t)b*4096 + (mi*16+c16)*64 + kh*32 + kg*8);
      acc[mi] = MFMA16(af, bf, acc[mi]);
    }
  }
  const int px = px0 + w*16 + c16;
  unsigned short* ob = out0 + (size_t)b*HW*64 + (size_t)px*64;
  #pragma unroll
  for(int mi=0; mi<4; ++mi){
    const int cb = mi*16 + kg*4;
    s16x4 o;
    #pragma unroll
    for(int r=0;r<4;++r) o[r] = bfr(acc[mi][r] + beff[b*64 + cb + r]);
    *(s16x4*)(ob + cb) = o;
  }
}

// ---------------- conv3x3 64->64, implicit GEMM, 16x16 px tile, fused epilogues ----------------
template<int RELU,int RES,int ADDY,int F32OUT>
__global__ __launch_bounds__(256) void kconv(const unsigned short* __restrict__ src,
                                             const unsigned short* __restrict__ wp,
                                             const float* __restrict__ bias,
                                             const unsigned short* __restrict__ res,
                                             const float* __restrict__ yadd,
                                             void* __restrict__ dst){
  const int bid = blockIdx.x;
  const int wt = bid & 15, ht = (bid >> 4) & 15, b = bid >> 8;
  const int h0 = ht*16, w0 = wt*16;
  __shared__ unsigned short lds[324*64];
  const int t = threadIdx.x;
  const unsigned short* sb = src + (size_t)b*HW*64;
  for(int c = t; c < 2592; c += 256){
    int pix = c >> 3, cg = c & 7;
    int lr = pix / 18, lc = pix - lr*18;
    int gh = h0 - 1 + lr, gw = w0 - 1 + lc;
    s16x8 v = {0,0,0,0,0,0,0,0};
    if((unsigned)gh < 256u && (unsigned)gw < 256u)
      v = *(const s16x8*)(sb + (size_t)(gh*256+gw)*64 + cg*8);
    int byte = pix*128 + ((cg*16) ^ ((pix&7)<<4));
    *(s16x8*)((char*)lds + byte) = v;
  }
  __syncthreads();
  const int w = t >> 6, l = t & 63, c16 = l & 15, kg = l >> 4;
  f32x4 acc[4][4];
  #pragma unroll
  for(int mi=0;mi<4;++mi)
    #pragma unroll
    for(int ni=0;ni<4;++ni) acc[mi][ni]=(f32x4){0.f,0.f,0.f,0.f};
  #pragma unroll
  for(int tap=0; tap<9; ++tap){
    const int dh = tap/3, dw = tap - dh*3;
    #pragma unroll
    for(int kh=0; kh<2; ++kh){
      s16x8 a[4];
      const unsigned short* wb = wp + tap*4096 + kh*32 + kg*8;
      #pragma unroll
      for(int mi=0;mi<4;++mi) a[mi] = *(const s16x8*)(wb + (mi*16 + c16)*64);
      s16x8 bf[4];
      #pragma unroll
      for(int ni=0;ni<4;++ni){
        int pix = (w*4 + ni + dh)*18 + (c16 + dw);
        int byte = pix*128 + (((kh*32 + kg*8)*2) ^ ((pix&7)<<4));
        bf[ni] = *(const s16x8*)((char*)lds + byte);
      }
      #pragma unroll
      for(int mi=0;mi<4;++mi)
        #pragma unroll
        for(int ni=0;ni<4;++ni)
          acc[mi][ni] = MFMA16(a[mi], bf[ni], acc[mi][ni]);
    }
  }
  #pragma unroll
  for(int ni=0; ni<4; ++ni){
    const int gh = h0 + w*4 + ni, gw = w0 + c16;
    const int px = gh*256 + gw;
    #pragma unroll
    for(int mi=0; mi<4; ++mi){
      const int cb = mi*16 + kg*4;
      float v[4];
      #pragma unroll
      for(int r=0;r<4;++r) v[r] = acc[mi][ni][r] + bias[cb+r];
      if(RELU){
        #pragma unroll
        for(int r=0;r<4;++r) v[r] = fmaxf(v[r], 0.f);
      }
      if(RES){
        s16x4 rv = *(const s16x4*)(res + (size_t)b*HW*64 + (size_t)px*64 + cb);
        #pragma unroll
        for(int r=0;r<4;++r) v[r] += b2f(rv[r]);
      }
      if(ADDY){
        #pragma unroll
        for(int r=0;r<4;++r) v[r] += yadd[(size_t)(b*64 + cb + r)*HW + px];
      }
      if(F32OUT){
        float* o = (float*)dst;
        #pragma unroll
        for(int r=0;r<4;++r) o[(size_t)(b*64 + cb + r)*HW + px] = v[r];
      } else {
        unsigned short* o = (unsigned short*)dst;
        s16x4 ov;
        #pragma unroll
        for(int r=0;r<4;++r) ov[r] = bfr(v[r]);
        *(s16x4*)(o + (size_t)b*HW*64 + (size_t)px*64 + cb) = ov;
      }
    }
  }
}

extern "C" void kernel_launch(void* const* d_in, const int* in_sizes, int n_in,
                              void* d_out, int out_size, void* d_ws, size_t ws_size,
                              hipStream_t stream){
  const float* x    = (const float*)d_in[0];
  const float* y    = (const float*)d_in[1];
  const float* qw   = (const float*)d_in[2];
  const float* qb   = (const float*)d_in[3];
  const float* kw   = (const float*)d_in[4];
  const float* kb   = (const float*)d_in[5];
  const float* vw   = (const float*)d_in[6];
  const float* vb   = (const float*)d_in[7];
  const float* r1w1 = (const float*)d_in[8];
  const float* r1b1 = (const float*)d_in[9];
  const float* r1w2 = (const float*)d_in[10];
  const float* r1b2 = (const float*)d_in[11];
  const float* r2w1 = (const float*)d_in[12];
  const float* r2b1 = (const float*)d_in[13];
  const float* r2w2 = (const float*)d_in[14];
  const float* r2b2 = (const float*)d_in[15];

  char* ws = (char*)d_ws;
  const size_t BUFB_OFF = (1u<<20) + (size_t)8*HW*64*2;          // 1MB + 64MB
  unsigned short* Wb   = (unsigned short*)(ws + 397312);
  float*          beff = (float*)(ws + 462848);
  unsigned short* wp   = (unsigned short*)(ws + 464896);
  unsigned short* bufA = (unsigned short*)(ws + (1u<<20));
  unsigned short* bufB = (unsigned short*)(ws + BUFB_OFF);
  unsigned short* bufC = bufB + (size_t)8*HW*64;
  float* part = (float*)bufB;   // Gram partials alias bufB (consumed before bufB is written)

  kpack<<<576,256,0,stream>>>(r1w1,r1w2,r2w1,r2w2,wp);
  kgram<<<1024,256,0,stream>>>(x,y,part);
  kattn<<<8,256,0,stream>>>(qw,qb,kw,kb,vw,vb,part,Wb,beff);
  k1x1<<<8192,256,0,stream>>>(y,Wb,beff,bufA);
  kconv<1,0,0,0><<<2048,256,0,stream>>>(bufA, wp,         r1b1, nullptr, nullptr, bufB);
  kconv<0,1,0,0><<<2048,256,0,stream>>>(bufB, wp+9*4096,  r1b2, bufA,    nullptr, bufC);
  kconv<1,0,0,0><<<2048,256,0,stream>>>(bufC, wp+18*4096, r2b1, nullptr, nullptr, bufA);
  kconv<0,1,1,1><<<2048,256,0,stream>>>(bufA, wp+27*4096, r2b2, bufC,    y,       d_out);
}